// Round 24
// baseline (570.699 us; speedup 1.0000x reference)
//
#include <hip/hip_runtime.h>
#include <hip/hip_bf16.h>

// MoE E=64, top-2, T=8192, D=1024, DFF=1408. Round 24 (base = r23, single
// change: me_kernel fused away):
//  - gate reduces its 8 tokens' softmax vectors to a per-block partial sum
//    psum[block][64] (LDS pbuf, +2KB); probs array (2MB) deleted.
//  - finalize reduces the 1024 partials per expert in FIXED index order
//    (deterministic) -> l_aux. One fewer launch, -4MB traffic.
//  - ffn1/ffn2/combine = r23 (128x128 tiles, A-direct octet-major,
//    interleaved issue, aliased ffn1 LDS, compact eo + combine).

#define S_ 2048
#define B_ 4
#define D_ 1024
#define DFF_ 1408
#define E_ 64
#define T_ 8192
#define KTOP_ 2
#define NPAIR_ (T_*KTOP_)
#define PAD_ 384
#define ROWS_ (E_*PAD_)
#define NGB_ (T_/8)          // gate blocks = 1024

#define BM 128
#define BN 128
#define BK 32

typedef __attribute__((ext_vector_type(8))) short short8;
typedef __attribute__((ext_vector_type(4))) short s16x4;
typedef __attribute__((ext_vector_type(4))) float f32x4;
typedef __attribute__((ext_vector_type(4))) unsigned short us4;

// ---------------- workspace layout (bytes) ----------------
constexpr size_t OFF_PSUM   = 0;                                  // NGB*64 f32 = 256KB
constexpr size_t OFF_COUNTS = OFF_PSUM + (size_t)NGB_*64*4;       // 64 int (+pad)
constexpr size_t OFF_PAIRE  = OFF_COUNTS + 512;                   // NPAIR int
constexpr size_t OFF_PAIRM  = OFF_PAIRE + (size_t)NPAIR_*4;       // NPAIR int
constexpr size_t OFF_PAIRW  = OFF_PAIRM + (size_t)NPAIR_*4;       // NPAIR f32
constexpr size_t OFF_XBUF   = OFF_PAIRW + (size_t)NPAIR_*4;       // ROWS*D bf16 (xbufO, later eoO)
constexpr size_t OFF_H      = OFF_XBUF + (size_t)ROWS_*D_*2;      // ROWS*DFF bf16

__device__ __forceinline__ short f2bfs(float f) {
  union { __hip_bfloat16 h; short s; } u;
  u.h = __float2bfloat16(f);
  return u.s;
}
__device__ __forceinline__ float bf2f(unsigned short u) {
  unsigned v = ((unsigned)u) << 16;
  return __uint_as_float(v);
}

// granule XOR swizzle for B staging (conflict-free frag reads)
__device__ __forceinline__ int SWZ(int g) { return g ^ (((g >> 4) & 3) << 1); }

#define BARS() do {                                  \
    __builtin_amdgcn_sched_barrier(0);               \
    __builtin_amdgcn_s_barrier();                    \
    __builtin_amdgcn_sched_barrier(0);               \
  } while (0)
#define BARX() __builtin_amdgcn_s_barrier()
#define WAIT_LGKM0() asm volatile("s_waitcnt lgkmcnt(0)" ::: "memory")

// ---------------- gate + fused scatter + me-partials ----------------
__device__ __forceinline__ float softmax64(float acc, int lane) {
  float m = acc;
  for (int o = 32; o; o >>= 1) m = fmaxf(m, __shfl_xor(m, o));
  float p = expf(acc - m);
  float s = p;
  for (int o = 32; o; o >>= 1) s += __shfl_xor(s, o);
  return p / s;
}

__global__ __launch_bounds__(256) void gate_kernel(
    const float* __restrict__ x, const float* __restrict__ Wg,
    float* __restrict__ psum, int* __restrict__ counts,
    int* __restrict__ pairE, int* __restrict__ pairM, float* __restrict__ pairW,
    unsigned short* __restrict__ xbufO) {
  int t0 = blockIdx.x * 8;
  int tid = threadIdx.x;
  int lane = tid & 63, wv = tid >> 6;
  __shared__ float tk[8][D_];
  __shared__ float pbuf[8][64];
  __shared__ int sE[8][2];
  __shared__ int sM[8][2];
  for (int u = tid; u < 8 * (D_ / 4); u += 256) {
    int r = u >> 8, c4 = u & 255;
    int t = t0 + r;
    int b = t >> 11, s = t & (S_ - 1);
    ((float4*)tk[r])[c4] = ((const float4*)(x + (size_t)(s * B_ + b) * D_))[c4];
  }
  __syncthreads();
  const float* tkA = tk[2 * wv];
  const float* tkB = tk[2 * wv + 1];
  float acc0 = 0.f, acc1 = 0.f;
  #pragma unroll 8
  for (int d = 0; d < D_; ++d) {
    float w = Wg[(size_t)d * E_ + lane];
    acc0 += tkA[d] * w;
    acc1 += tkB[d] * w;
  }
  #pragma unroll
  for (int half = 0; half < 2; ++half) {
    float p = softmax64(half ? acc1 : acc0, lane);
    int tkn = 2 * wv + half;
    int t = t0 + tkn;
    pbuf[tkn][lane] = p;
    float v1 = p; int i1 = lane;
    for (int o = 32; o; o >>= 1) {
      float ov = __shfl_xor(v1, o); int oi = __shfl_xor(i1, o);
      if (ov > v1 || (ov == v1 && oi < i1)) { v1 = ov; i1 = oi; }
    }
    float v2 = (lane == i1) ? -1.f : p; int i2 = lane;
    for (int o = 32; o; o >>= 1) {
      float ov = __shfl_xor(v2, o); int oi = __shfl_xor(i2, o);
      if (ov > v2 || (ov == v2 && oi < i2)) { v2 = ov; i2 = oi; }
    }
    if (lane == 0) {
      float wsum = v1 + v2;
      int s1 = atomicAdd(&counts[i1], 1);
      int s2 = atomicAdd(&counts[i2], 1);
      int m1 = (s1 < PAD_) ? s1 : -1;
      int m2 = (s2 < PAD_) ? s2 : -1;
      pairE[2 * t]     = i1; pairM[2 * t]     = m1; pairW[2 * t]     = v1 / wsum;
      pairE[2 * t + 1] = i2; pairM[2 * t + 1] = m2; pairW[2 * t + 1] = v2 / wsum;
      sE[tkn][0] = i1; sM[tkn][0] = m1;
      sE[tkn][1] = i2; sM[tkn][1] = m2;
    }
  }
  __syncthreads();
  // me partial: fixed-order sum of the block's 8 softmax rows
  if (tid < 64) {
    float a = 0.f;
    #pragma unroll
    for (int r = 0; r < 8; ++r) a += pbuf[r][tid];
    psum[(size_t)blockIdx.x * 64 + tid] = a;
  }
  // fused scatter: 16 (token,expert) rows; half-block per row, granule/thread
  int hh = tid >> 7, t7 = tid & 127;
  #pragma unroll
  for (int pp = 0; pp < 8; ++pp) {
    int pr = 2 * pp + hh;
    int tkn = pr >> 1, j = pr & 1;
    int e = sE[tkn][j];
    int m = sM[tkn][j];
    if (m >= 0) {
      const float* src = tk[tkn] + t7 * 8;
      short8 g;
      #pragma unroll
      for (int k = 0; k < 8; ++k) g[k] = f2bfs(src[k]);
      *(short8*)(xbufO + (size_t)e * D_ * PAD_ + ((size_t)t7 * PAD_ + m) * 8) = g;
    }
  }
}

// ---------------- finalize: deterministic me reduce + l_aux ----------------
__global__ __launch_bounds__(64) void finalize_kernel(
    const int* __restrict__ counts, const float* __restrict__ psum,
    float* __restrict__ laux_out) {
  int lane = threadIdx.x;
  float mesum = 0.f;
  for (int b = 0; b < NGB_; ++b) mesum += psum[(size_t)b * 64 + lane];
  float contrib = (mesum / (float)T_) * ((float)counts[lane] / (float)(T_ * KTOP_));
  for (int o = 32; o; o >>= 1) contrib += __shfl_xor(contrib, o);
  if (lane == 0) laux_out[0] = (float)E_ * contrib;
}

// ---------------- ffn1: 128x128 tile, 32KB aliased LDS (r23) ----------------
__global__ __launch_bounds__(256, 2) void ffn1_kernel(
    const unsigned short* __restrict__ xbufO, const float* __restrict__ W1,
    const float* __restrict__ W3, const int* __restrict__ counts,
    unsigned short* __restrict__ hO) {
  // grid 2112 = 8 xcd x (8 eg x 11 ni x 3 mb), mb fastest (W L2 sharing)
  int bid = blockIdx.x;
  int r = bid & 7, u = bid >> 3;
  int mb = u % 3; int v = u / 3;
  int ni = v % 11; int eg = v / 11;
  int e = eg * 8 + r;
  int n0 = ni * BN;
  int m0 = mb * BM;
  int Me = min(counts[e], PAD_);
  if (m0 >= Me) return;                  // block-granular pad skip

  const unsigned short* AO = xbufO + (size_t)e * D_ * PAD_;
  const float* B1p = W1 + (size_t)e * D_ * DFF_ + n0;
  const float* B3p = W3 + (size_t)e * D_ * DFF_ + n0;
  unsigned short* hE = hO + (size_t)e * PAD_ * DFF_;

  // 32KB arena: K-loop = {B1s, B3s}; epilogue = Hb (aliased)
  __shared__ char smem[32768];
  short* B1s = (short*)smem;
  short* B3s = (short*)(smem + 16384);
  short* Hb  = (short*)smem;

  int tid = threadIdx.x;
  int lane = tid & 63;
  int wv = tid >> 6, wr = wv >> 1, wc = wv & 1;

  // B staging: tid<128 -> W1, >=128 -> W3. Thread: 8 k-rows x 4 cols.
  int msel = tid >> 7;
  int t7 = tid & 127;
  int col4 = t7 & 31;
  int krow0 = (t7 >> 5) << 3;
  const float* qB = (msel ? B3p : B1p) + (size_t)krow0 * DFF_ + col4 * 4;
  char* Bdst = (char*)(msel ? B3s : B1s);
  int kseg = krow0 >> 3;
  int boffc[4];
  #pragma unroll
  for (int cc = 0; cc < 4; ++cc) {
    int c = col4 * 4 + cc;
    boffc[cc] = ((c >> 4) << 10) + (SWZ((kseg << 4) + (c & 15)) << 4);
  }

  // A-direct: frag f=wr*4+mi; lane: row m0+f*16+(lane&15), octet 4t+(lane>>4)
  const unsigned short* qa =
      AO + (((size_t)(lane >> 4)) * PAD_ + m0 + (wr << 6) + (lane & 15)) * 8;

  short8 afE[4], afO[4];
  f32x4 fBE[8], fBO[8];
  f32x4 acc1[4][4] = {};
  f32x4 acc3[4][4] = {};

#define F1_ALOAD(SET) do {                                               \
    _Pragma("unroll")                                                    \
    for (int mi = 0; mi < 4; ++mi)                                       \
      af##SET[mi] = *(const short8*)(qa + mi * 128);                     \
    qa += (size_t)4 * PAD_ * 8;                                          \
  } while (0)

#define F1_BLOAD(SET) do {                                               \
    _Pragma("unroll")                                                    \
    for (int j = 0; j < 8; ++j)                                          \
      fB##SET[j] = *(const f32x4*)(qB + (size_t)j * DFF_);               \
    qB += (size_t)BK * DFF_;                                             \
  } while (0)

#define F1_BWRITE(SET, BUF) do {                                         \
    _Pragma("unroll")                                                    \
    for (int cc = 0; cc < 4; ++cc) {                                     \
      short8 w;                                                          \
      _Pragma("unroll")                                                  \
      for (int j = 0; j < 8; ++j) w[j] = f2bfs(fB##SET[j][cc]);          \
      *(short8*)(Bdst + (BUF)*8192 + boffc[cc]) = w;                     \
    }                                                                    \
  } while (0)

#define F1_MFMA(BUF, SET) do {                                           \
    int lsw = SWZ(lane) << 4;                                            \
    __builtin_amdgcn_s_setprio(1);                                       \
    _Pragma("unroll")                                                    \
    for (int q = 0; q < 4; ++q) {                                        \
      short8 bf1 = *(const short8*)((char*)B1s + (BUF)*8192 + (((wc << 2) + q) << 10) + lsw); \
      short8 bf3 = *(const short8*)((char*)B3s + (BUF)*8192 + (((wc << 2) + q) << 10) + lsw); \
      _Pragma("unroll")                                                  \
      for (int mi = 0; mi < 4; ++mi) {                                   \
        acc1[mi][q] = __builtin_amdgcn_mfma_f32_16x16x32_bf16(af##SET[mi], bf1, acc1[mi][q], 0, 0, 0); \
        acc3[mi][q] = __builtin_amdgcn_mfma_f32_16x16x32_bf16(af##SET[mi], bf3, acc3[mi][q], 0, 0, 0); \
      }                                                                  \
    }                                                                    \
    __builtin_amdgcn_s_setprio(0);                                       \
  } while (0)

  // 32 K-tiles, depth-2, interleaved issue
  F1_ALOAD(E); F1_BLOAD(E);      // t0
  F1_ALOAD(O); F1_BLOAD(O);      // t1
  for (int it = 0; it < 15; ++it) {
    F1_BWRITE(E, 0); WAIT_LGKM0(); BARS();
    F1_BLOAD(E);
    F1_MFMA(0, E);
    F1_ALOAD(E);
    BARX();
    F1_BWRITE(O, 1); WAIT_LGKM0(); BARS();
    F1_BLOAD(O);
    F1_MFMA(1, O);
    F1_ALOAD(O);
    BARX();
  }
  F1_BWRITE(E, 0); WAIT_LGKM0(); BARS(); F1_MFMA(0, E); BARX();
  F1_BWRITE(O, 1); WAIT_LGKM0(); BARS(); F1_MFMA(1, O);

  // epilogue: silu(acc1)*acc3 -> Hb (aliased arena) -> octet-major hO
  __syncthreads();
  int lr = (lane >> 4) << 2, lc = lane & 15;
  #pragma unroll
  for (int mi = 0; mi < 4; ++mi) {
    #pragma unroll
    for (int j = 0; j < 4; ++j) {
      int m = ((wr << 2) + mi) * 16 + lr + j;       // local row 0..127
      #pragma unroll
      for (int q = 0; q < 4; ++q) {
        int c = (wc << 6) + (q << 4) + lc;          // local col 0..127
        float a = acc1[mi][q][j];
        float gt = a / (1.f + __expf(-a));
        Hb[((size_t)(c >> 3) * BM + m) * 8 + (c & 7)] = f2bfs(gt * acc3[mi][q][j]);
      }
    }
  }
  __syncthreads();
  int co = tid >> 4, ml0 = (tid & 15) << 3;         // 16 col-octets x 16 row-groups
  size_t fo = (size_t)(n0 >> 3) + co;
  #pragma unroll
  for (int i = 0; i < 8; ++i) {
    int ml = ml0 + i;
    short8 vq = *(const short8*)(Hb + ((size_t)co * BM + ml) * 8);
    *(short8*)(hE + (fo * PAD_ + m0 + ml) * 8) = vq;
  }
}

// ---------------- ffn2: 128x128 tile, compact bf16 eo store (r22) ----------------
__global__ __launch_bounds__(256, 3) void ffn2_kernel(
    const unsigned short* __restrict__ hO, const float* __restrict__ W2,
    const int* __restrict__ counts, unsigned short* __restrict__ eoO) {
  // grid 1536 = 8 xcd x (8 eg x 8 ni x 3 mb), mb fastest
  int bid = blockIdx.x;
  int r = bid & 7, u = bid >> 3;
  int mb = u % 3; int v = u / 3;
  int ni = v % 8; int eg = v / 8;
  int e = eg * 8 + r;
  int n0 = ni * BN;
  int m0 = mb * BM;
  int Me = min(counts[e], PAD_);
  if (m0 >= Me) return;

  const unsigned short* AO = hO + (size_t)e * PAD_ * DFF_;
  const float* Bw = W2 + (size_t)e * DFF_ * D_ + n0;

  __shared__ short Bs[2 * BK * BN];    // 2 x 8KB

  int tid = threadIdx.x;
  int lane = tid & 63;
  int wv = tid >> 6, wr = wv >> 1, wc = wv & 1;

  // B staging: all 256 threads; thread: 4 k-rows x 4 cols.
  int col4 = tid & 31;
  int krow0 = (tid >> 5) << 2;
  const float* qB = Bw + (size_t)krow0 * D_ + col4 * 4;
  int kseg = krow0 >> 3, khalf8 = ((krow0 >> 2) & 1) << 3;
  int boffc[4];
  #pragma unroll
  for (int cc = 0; cc < 4; ++cc) {
    int c = col4 * 4 + cc;
    boffc[cc] = ((c >> 4) << 10) + (SWZ((kseg << 4) + (c & 15)) << 4) + khalf8;
  }

  const unsigned short* qa =
      AO + (((size_t)(lane >> 4)) * PAD_ + m0 + (wr << 6) + (lane & 15)) * 8;

  short8 afE[4], afO[4];
  f32x4 fBE[4], fBO[4];
  f32x4 acc[4][4] = {};

#define F2_ALOAD(SET) do {                                               \
    _Pragma("unroll")                                                    \
    for (int mi = 0; mi < 4; ++mi)                                       \
      af##SET[mi] = *(const short8*)(qa + mi * 128);                     \
    qa += (size_t)4 * PAD_ * 8;                                          \
  } while (0)

#define F2_BLOAD(SET) do {                                               \
    _Pragma("unroll")                                                    \
    for (int j = 0; j < 4; ++j)                                          \
      fB##SET[j] = *(const f32x4*)(qB + (size_t)j * D_);                 \
    qB += (size_t)BK * D_;                                               \
  } while (0)

#define F2_BWRITE(SET, BUF) do {                                         \
    _Pragma("unroll")                                                    \
    for (int cc = 0; cc < 4; ++cc) {                                     \
      s16x4 w;                                                           \
      _Pragma("unroll")                                                  \
      for (int j = 0; j < 4; ++j) w[j] = f2bfs(fB##SET[j][cc]);          \
      *(s16x4*)((char*)Bs + (BUF)*8192 + boffc[cc]) = w;                 \
    }                                                                    \
  } while (0)

#define F2_MFMA(BUF, SET) do {                                           \
    int lsw = SWZ(lane) << 4;                                            \
    __builtin_amdgcn_s_setprio(1);                                       \
    _Pragma("unroll")                                                    \
    for (int q = 0; q < 4; ++q) {                                        \
      short8 bfr = *(const short8*)((char*)Bs + (BUF)*8192 + (((wc << 2) + q) << 10) + lsw); \
      _Pragma("unroll")                                                  \
      for (int mi = 0; mi < 4; ++mi)                                     \
        acc[mi][q] = __builtin_amdgcn_mfma_f32_16x16x32_bf16(af##SET[mi], bfr, acc[mi][q], 0, 0, 0); \
    }                                                                    \
    __builtin_amdgcn_s_setprio(0);                                       \
  } while (0)

  // 44 K-tiles, depth-2, interleaved issue
  F2_ALOAD(E); F2_BLOAD(E);
  F2_ALOAD(O); F2_BLOAD(O);
  for (int it = 0; it < 21; ++it) {
    F2_BWRITE(E, 0); WAIT_LGKM0(); BARS();
    F2_BLOAD(E);
    F2_MFMA(0, E);
    F2_ALOAD(E);
    BARX();
    F2_BWRITE(O, 1); WAIT_LGKM0(); BARS();
    F2_BLOAD(O);
    F2_MFMA(1, O);
    F2_ALOAD(O);
    BARX();
  }
  F2_BWRITE(E, 0); WAIT_LGKM0(); BARS(); F2_MFMA(0, E); BARX();
  F2_BWRITE(O, 1); WAIT_LGKM0(); BARS(); F2_MFMA(1, O);

  // epilogue: coalesced bf16 store of raw acc to eoO[e][m][D]
  unsigned short* eoE = eoO + (size_t)e * PAD_ * D_;
  int lr = (lane >> 4) << 2, lc = lane & 15;
  #pragma unroll
  for (int mi = 0; mi < 4; ++mi) {
    #pragma unroll
    for (int j = 0; j < 4; ++j) {
      int m = m0 + ((wr << 2) + mi) * 16 + lr + j;
      if (m < Me) {
        unsigned short* op = eoE + (size_t)m * D_ + n0 + (wc << 6) + lc;
        #pragma unroll
        for (int q = 0; q < 4; ++q)
          op[q << 4] = (unsigned short)f2bfs(acc[mi][q][j]);
      }
    }
  }
}

// ---------------- combine: y[t] = w1*eo1 + w2*eo2 ----------------
__global__ __launch_bounds__(256) void combine_kernel(
    const unsigned short* __restrict__ eoO, const int* __restrict__ pairE,
    const int* __restrict__ pairM, const float* __restrict__ pairW,
    float* __restrict__ y) {
  int t = blockIdx.x * 4 + (threadIdx.x >> 6);
  int lane = threadIdx.x & 63;
  int e1 = pairE[2 * t], m1 = pairM[2 * t];
  int e2 = pairE[2 * t + 1], m2 = pairM[2 * t + 1];
  float w1 = pairW[2 * t], w2 = pairW[2 * t + 1];
  float out[16];
  #pragma unroll
  for (int i = 0; i < 16; ++i) out[i] = 0.f;
  if (m1 >= 0) {
    const unsigned short* rp = eoO + ((size_t)e1 * PAD_ + m1) * D_ + lane * 16;
    short8 a = *(const short8*)rp, b = *(const short8*)(rp + 8);
    #pragma unroll
    for (int i = 0; i < 8; ++i) {
      out[i]     += w1 * bf2f((unsigned short)a[i]);
      out[8 + i] += w1 * bf2f((unsigned short)b[i]);
    }
  }
  if (m2 >= 0) {
    const unsigned short* rp = eoO + ((size_t)e2 * PAD_ + m2) * D_ + lane * 16;
    short8 a = *(const short8*)rp, b = *(const short8*)(rp + 8);
    #pragma unroll
    for (int i = 0; i < 8; ++i) {
      out[i]     += w2 * bf2f((unsigned short)a[i]);
      out[8 + i] += w2 * bf2f((unsigned short)b[i]);
    }
  }
  int b = t >> 11, s = t & (S_ - 1);
  float* yp = y + (size_t)(s * B_ + b) * D_ + lane * 16;
  #pragma unroll
  for (int v = 0; v < 4; ++v) {
    float4 o4 = make_float4(out[v * 4], out[v * 4 + 1], out[v * 4 + 2], out[v * 4 + 3]);
    *(float4*)(yp + v * 4) = o4;
  }
}

extern "C" void kernel_launch(void* const* d_in, const int* in_sizes, int n_in,
                              void* d_out, int out_size, void* d_ws, size_t ws_size,
                              hipStream_t stream) {
  const float* x  = (const float*)d_in[0];
  const float* Wg = (const float*)d_in[1];
  const float* W1 = (const float*)d_in[2];
  const float* W3 = (const float*)d_in[3];
  const float* W2 = (const float*)d_in[4];
  float* y = (float*)d_out;
  float* laux = y + (size_t)S_ * B_ * D_;

  char* ws = (char*)d_ws;
  float* psum   = (float*)(ws + OFF_PSUM);
  int*   counts = (int*)  (ws + OFF_COUNTS);
  int*   pairE  = (int*)  (ws + OFF_PAIRE);
  int*   pairM  = (int*)  (ws + OFF_PAIRM);
  float* pairW  = (float*)(ws + OFF_PAIRW);
  unsigned short* xbufO = (unsigned short*)(ws + OFF_XBUF);  // also eoO
  unsigned short* hO    = (unsigned short*)(ws + OFF_H);

  hipMemsetAsync(counts, 0, 512, stream);

  gate_kernel<<<NGB_, 256, 0, stream>>>(x, Wg, psum, counts, pairE, pairM, pairW, xbufO);
  finalize_kernel<<<1, 64, 0, stream>>>(counts, psum, laux);
  ffn1_kernel<<<8 * 8 * 11 * 3, 256, 0, stream>>>(xbufO, W1, W3, counts, hO);
  ffn2_kernel<<<8 * 8 * 8 * 3, 256, 0, stream>>>(hO, W2, counts, xbufO);  // eoO aliases xbufO
  combine_kernel<<<T_ / 4, 256, 0, stream>>>(xbufO, pairE, pairM, pairW, y);
}

// Round 25
// 566.858 us; speedup vs baseline: 1.0068x; 1.0068x over previous
//
#include <hip/hip_runtime.h>
#include <hip/hip_bf16.h>

// MoE E=64, top-2, T=8192, D=1024, DFF=1408. Round 25 = FINAL (revert to
// r23, the best measured config, 566 us):
//  - fused gate+scatter (octet-major bf16 xbuf), probs + me_kernel restored
//    (r24's me-fusion was neutral-negative).
//  - ffn1: 128x128 tile, A-direct octet-major, interleaved load-issue,
//    32KB aliased LDS (B-dbuf / epilogue Hb).
//  - ffn2: 128x128 tile, compact bf16 eo store (no atomics) + combine.
// Session: 2875 -> 566 us. FFNs at the 2-phase-schedule structural plateau
// (10 single-variable levers each <2%; no saturated pipe in counters).

#define S_ 2048
#define B_ 4
#define D_ 1024
#define DFF_ 1408
#define E_ 64
#define T_ 8192
#define KTOP_ 2
#define NPAIR_ (T_*KTOP_)
#define PAD_ 384
#define ROWS_ (E_*PAD_)

#define BM 128
#define BN 128
#define BK 32

typedef __attribute__((ext_vector_type(8))) short short8;
typedef __attribute__((ext_vector_type(4))) short s16x4;
typedef __attribute__((ext_vector_type(4))) float f32x4;
typedef __attribute__((ext_vector_type(4))) unsigned short us4;

// ---------------- workspace layout (bytes) ----------------
constexpr size_t OFF_PROBS  = 0;                                  // T*E f32
constexpr size_t OFF_COUNTS = OFF_PROBS + (size_t)T_*E_*4;        // 64 int (+pad)
constexpr size_t OFF_MESUM  = OFF_COUNTS + 512;                   // 64 f32
constexpr size_t OFF_PAIRE  = OFF_MESUM + 256;                    // NPAIR int
constexpr size_t OFF_PAIRM  = OFF_PAIRE + (size_t)NPAIR_*4;       // NPAIR int
constexpr size_t OFF_PAIRW  = OFF_PAIRM + (size_t)NPAIR_*4;       // NPAIR f32
constexpr size_t OFF_XBUF   = OFF_PAIRW + (size_t)NPAIR_*4;       // ROWS*D bf16 (xbufO, later eoO)
constexpr size_t OFF_H      = OFF_XBUF + (size_t)ROWS_*D_*2;      // ROWS*DFF bf16

__device__ __forceinline__ short f2bfs(float f) {
  union { __hip_bfloat16 h; short s; } u;
  u.h = __float2bfloat16(f);
  return u.s;
}
__device__ __forceinline__ float bf2f(unsigned short u) {
  unsigned v = ((unsigned)u) << 16;
  return __uint_as_float(v);
}

// granule XOR swizzle for B staging (conflict-free frag reads)
__device__ __forceinline__ int SWZ(int g) { return g ^ (((g >> 4) & 3) << 1); }

#define BARS() do {                                  \
    __builtin_amdgcn_sched_barrier(0);               \
    __builtin_amdgcn_s_barrier();                    \
    __builtin_amdgcn_sched_barrier(0);               \
  } while (0)
#define BARX() __builtin_amdgcn_s_barrier()
#define WAIT_LGKM0() asm volatile("s_waitcnt lgkmcnt(0)" ::: "memory")

// ---------------- gate + fused scatter ----------------
__device__ __forceinline__ float softmax64(float acc, int lane) {
  float m = acc;
  for (int o = 32; o; o >>= 1) m = fmaxf(m, __shfl_xor(m, o));
  float p = expf(acc - m);
  float s = p;
  for (int o = 32; o; o >>= 1) s += __shfl_xor(s, o);
  return p / s;
}

__global__ __launch_bounds__(256) void gate_kernel(
    const float* __restrict__ x, const float* __restrict__ Wg,
    float* __restrict__ probs, int* __restrict__ counts,
    int* __restrict__ pairE, int* __restrict__ pairM, float* __restrict__ pairW,
    unsigned short* __restrict__ xbufO) {
  int t0 = blockIdx.x * 8;
  int tid = threadIdx.x;
  int lane = tid & 63, wv = tid >> 6;
  __shared__ float tk[8][D_];
  __shared__ int sE[8][2];
  __shared__ int sM[8][2];
  for (int u = tid; u < 8 * (D_ / 4); u += 256) {
    int r = u >> 8, c4 = u & 255;
    int t = t0 + r;
    int b = t >> 11, s = t & (S_ - 1);
    ((float4*)tk[r])[c4] = ((const float4*)(x + (size_t)(s * B_ + b) * D_))[c4];
  }
  __syncthreads();
  const float* tkA = tk[2 * wv];
  const float* tkB = tk[2 * wv + 1];
  float acc0 = 0.f, acc1 = 0.f;
  #pragma unroll 8
  for (int d = 0; d < D_; ++d) {
    float w = Wg[(size_t)d * E_ + lane];
    acc0 += tkA[d] * w;
    acc1 += tkB[d] * w;
  }
  #pragma unroll
  for (int half = 0; half < 2; ++half) {
    float p = softmax64(half ? acc1 : acc0, lane);
    int tkn = 2 * wv + half;
    int t = t0 + tkn;
    probs[(size_t)t * E_ + lane] = p;
    float v1 = p; int i1 = lane;
    for (int o = 32; o; o >>= 1) {
      float ov = __shfl_xor(v1, o); int oi = __shfl_xor(i1, o);
      if (ov > v1 || (ov == v1 && oi < i1)) { v1 = ov; i1 = oi; }
    }
    float v2 = (lane == i1) ? -1.f : p; int i2 = lane;
    for (int o = 32; o; o >>= 1) {
      float ov = __shfl_xor(v2, o); int oi = __shfl_xor(i2, o);
      if (ov > v2 || (ov == v2 && oi < i2)) { v2 = ov; i2 = oi; }
    }
    if (lane == 0) {
      float wsum = v1 + v2;
      int s1 = atomicAdd(&counts[i1], 1);
      int s2 = atomicAdd(&counts[i2], 1);
      int m1 = (s1 < PAD_) ? s1 : -1;
      int m2 = (s2 < PAD_) ? s2 : -1;
      pairE[2 * t]     = i1; pairM[2 * t]     = m1; pairW[2 * t]     = v1 / wsum;
      pairE[2 * t + 1] = i2; pairM[2 * t + 1] = m2; pairW[2 * t + 1] = v2 / wsum;
      sE[tkn][0] = i1; sM[tkn][0] = m1;
      sE[tkn][1] = i2; sM[tkn][1] = m2;
    }
  }
  __syncthreads();
  // fused scatter: 16 (token,expert) rows; half-block per row, granule/thread
  int hh = tid >> 7, t7 = tid & 127;
  #pragma unroll
  for (int pp = 0; pp < 8; ++pp) {
    int pr = 2 * pp + hh;
    int tkn = pr >> 1, j = pr & 1;
    int e = sE[tkn][j];
    int m = sM[tkn][j];
    if (m >= 0) {
      const float* src = tk[tkn] + t7 * 8;
      short8 g;
      #pragma unroll
      for (int k = 0; k < 8; ++k) g[k] = f2bfs(src[k]);
      *(short8*)(xbufO + (size_t)e * D_ * PAD_ + ((size_t)t7 * PAD_ + m) * 8) = g;
    }
  }
}

// ---------------- me reduce ----------------
__global__ __launch_bounds__(256) void me_kernel(const float* __restrict__ probs,
                                                 float* __restrict__ mesum) {
  int e = blockIdx.x, tid = threadIdx.x;
  float a = 0.f;
  for (int t = tid; t < T_; t += 256) a += probs[(size_t)t * E_ + e];
  __shared__ float red[256];
  red[tid] = a; __syncthreads();
  for (int s = 128; s; s >>= 1) {
    if (tid < s) red[tid] += red[tid + s];
    __syncthreads();
  }
  if (tid == 0) mesum[e] = red[0];
}

// ---------------- finalize l_aux ----------------
__global__ __launch_bounds__(64) void finalize_kernel(
    const int* __restrict__ counts, const float* __restrict__ mesum,
    float* __restrict__ laux_out) {
  int lane = threadIdx.x;
  float contrib = (mesum[lane] / (float)T_) * ((float)counts[lane] / (float)(T_ * KTOP_));
  for (int o = 32; o; o >>= 1) contrib += __shfl_xor(contrib, o);
  if (lane == 0) laux_out[0] = (float)E_ * contrib;
}

// ---------------- ffn1: 128x128 tile, 32KB aliased LDS ----------------
__global__ __launch_bounds__(256, 2) void ffn1_kernel(
    const unsigned short* __restrict__ xbufO, const float* __restrict__ W1,
    const float* __restrict__ W3, const int* __restrict__ counts,
    unsigned short* __restrict__ hO) {
  // grid 2112 = 8 xcd x (8 eg x 11 ni x 3 mb), mb fastest (W L2 sharing)
  int bid = blockIdx.x;
  int r = bid & 7, u = bid >> 3;
  int mb = u % 3; int v = u / 3;
  int ni = v % 11; int eg = v / 11;
  int e = eg * 8 + r;
  int n0 = ni * BN;
  int m0 = mb * BM;
  int Me = min(counts[e], PAD_);
  if (m0 >= Me) return;                  // block-granular pad skip

  const unsigned short* AO = xbufO + (size_t)e * D_ * PAD_;
  const float* B1p = W1 + (size_t)e * D_ * DFF_ + n0;
  const float* B3p = W3 + (size_t)e * D_ * DFF_ + n0;
  unsigned short* hE = hO + (size_t)e * PAD_ * DFF_;

  // 32KB arena: K-loop = {B1s: 0..16K, B3s: 16K..32K}; epilogue = Hb (32KB)
  __shared__ char smem[32768];
  short* B1s = (short*)smem;
  short* B3s = (short*)(smem + 16384);
  short* Hb  = (short*)smem;

  int tid = threadIdx.x;
  int lane = tid & 63;
  int wv = tid >> 6, wr = wv >> 1, wc = wv & 1;

  // B staging: tid<128 -> W1, >=128 -> W3. Thread: 8 k-rows x 4 cols.
  int msel = tid >> 7;
  int t7 = tid & 127;
  int col4 = t7 & 31;
  int krow0 = (t7 >> 5) << 3;
  const float* qB = (msel ? B3p : B1p) + (size_t)krow0 * DFF_ + col4 * 4;
  char* Bdst = (char*)(msel ? B3s : B1s);
  int kseg = krow0 >> 3;
  int boffc[4];
  #pragma unroll
  for (int cc = 0; cc < 4; ++cc) {
    int c = col4 * 4 + cc;
    boffc[cc] = ((c >> 4) << 10) + (SWZ((kseg << 4) + (c & 15)) << 4);
  }

  // A-direct: frag f=wr*4+mi; lane: row m0+f*16+(lane&15), octet 4t+(lane>>4)
  const unsigned short* qa =
      AO + (((size_t)(lane >> 4)) * PAD_ + m0 + (wr << 6) + (lane & 15)) * 8;

  short8 afE[4], afO[4];
  f32x4 fBE[8], fBO[8];
  f32x4 acc1[4][4] = {};
  f32x4 acc3[4][4] = {};

#define F1_ALOAD(SET) do {                                               \
    _Pragma("unroll")                                                    \
    for (int mi = 0; mi < 4; ++mi)                                       \
      af##SET[mi] = *(const short8*)(qa + mi * 128);                     \
    qa += (size_t)4 * PAD_ * 8;                                          \
  } while (0)

#define F1_BLOAD(SET) do {                                               \
    _Pragma("unroll")                                                    \
    for (int j = 0; j < 8; ++j)                                          \
      fB##SET[j] = *(const f32x4*)(qB + (size_t)j * DFF_);               \
    qB += (size_t)BK * DFF_;                                             \
  } while (0)

#define F1_BWRITE(SET, BUF) do {                                         \
    _Pragma("unroll")                                                    \
    for (int cc = 0; cc < 4; ++cc) {                                     \
      short8 w;                                                          \
      _Pragma("unroll")                                                  \
      for (int j = 0; j < 8; ++j) w[j] = f2bfs(fB##SET[j][cc]);          \
      *(short8*)(Bdst + (BUF)*8192 + boffc[cc]) = w;                     \
    }                                                                    \
  } while (0)

#define F1_MFMA(BUF, SET) do {                                           \
    int lsw = SWZ(lane) << 4;                                            \
    __builtin_amdgcn_s_setprio(1);                                       \
    _Pragma("unroll")                                                    \
    for (int q = 0; q < 4; ++q) {                                        \
      short8 bf1 = *(const short8*)((char*)B1s + (BUF)*8192 + (((wc << 2) + q) << 10) + lsw); \
      short8 bf3 = *(const short8*)((char*)B3s + (BUF)*8192 + (((wc << 2) + q) << 10) + lsw); \
      _Pragma("unroll")                                                  \
      for (int mi = 0; mi < 4; ++mi) {                                   \
        acc1[mi][q] = __builtin_amdgcn_mfma_f32_16x16x32_bf16(af##SET[mi], bf1, acc1[mi][q], 0, 0, 0); \
        acc3[mi][q] = __builtin_amdgcn_mfma_f32_16x16x32_bf16(af##SET[mi], bf3, acc3[mi][q], 0, 0, 0); \
      }                                                                  \
    }                                                                    \
    __builtin_amdgcn_s_setprio(0);                                       \
  } while (0)

  // 32 K-tiles, depth-2, interleaved issue
  F1_ALOAD(E); F1_BLOAD(E);      // t0
  F1_ALOAD(O); F1_BLOAD(O);      // t1
  for (int it = 0; it < 15; ++it) {
    F1_BWRITE(E, 0); WAIT_LGKM0(); BARS();
    F1_BLOAD(E);
    F1_MFMA(0, E);
    F1_ALOAD(E);
    BARX();
    F1_BWRITE(O, 1); WAIT_LGKM0(); BARS();
    F1_BLOAD(O);
    F1_MFMA(1, O);
    F1_ALOAD(O);
    BARX();
  }
  F1_BWRITE(E, 0); WAIT_LGKM0(); BARS(); F1_MFMA(0, E); BARX();
  F1_BWRITE(O, 1); WAIT_LGKM0(); BARS(); F1_MFMA(1, O);

  // epilogue: silu(acc1)*acc3 -> Hb (aliased arena) -> octet-major hO
  __syncthreads();
  int lr = (lane >> 4) << 2, lc = lane & 15;
  #pragma unroll
  for (int mi = 0; mi < 4; ++mi) {
    #pragma unroll
    for (int j = 0; j < 4; ++j) {
      int m = ((wr << 2) + mi) * 16 + lr + j;       // local row 0..127
      #pragma unroll
      for (int q = 0; q < 4; ++q) {
        int c = (wc << 6) + (q << 4) + lc;          // local col 0..127
        float a = acc1[mi][q][j];
        float gt = a / (1.f + __expf(-a));
        Hb[((size_t)(c >> 3) * BM + m) * 8 + (c & 7)] = f2bfs(gt * acc3[mi][q][j]);
      }
    }
  }
  __syncthreads();
  int co = tid >> 4, ml0 = (tid & 15) << 3;         // 16 col-octets x 16 row-groups
  size_t fo = (size_t)(n0 >> 3) + co;
  #pragma unroll
  for (int i = 0; i < 8; ++i) {
    int ml = ml0 + i;
    short8 vq = *(const short8*)(Hb + ((size_t)co * BM + ml) * 8);
    *(short8*)(hE + (fo * PAD_ + m0 + ml) * 8) = vq;
  }
}

// ---------------- ffn2: 128x128 tile, compact bf16 eo store ----------------
__global__ __launch_bounds__(256, 3) void ffn2_kernel(
    const unsigned short* __restrict__ hO, const float* __restrict__ W2,
    const int* __restrict__ counts, unsigned short* __restrict__ eoO) {
  // grid 1536 = 8 xcd x (8 eg x 8 ni x 3 mb), mb fastest
  int bid = blockIdx.x;
  int r = bid & 7, u = bid >> 3;
  int mb = u % 3; int v = u / 3;
  int ni = v % 8; int eg = v / 8;
  int e = eg * 8 + r;
  int n0 = ni * BN;
  int m0 = mb * BM;
  int Me = min(counts[e], PAD_);
  if (m0 >= Me) return;

  const unsigned short* AO = hO + (size_t)e * PAD_ * DFF_;
  const float* Bw = W2 + (size_t)e * DFF_ * D_ + n0;

  __shared__ short Bs[2 * BK * BN];    // 2 x 8KB

  int tid = threadIdx.x;
  int lane = tid & 63;
  int wv = tid >> 6, wr = wv >> 1, wc = wv & 1;

  // B staging: all 256 threads; thread: 4 k-rows x 4 cols.
  int col4 = tid & 31;
  int krow0 = (tid >> 5) << 2;
  const float* qB = Bw + (size_t)krow0 * D_ + col4 * 4;
  int kseg = krow0 >> 3, khalf8 = ((krow0 >> 2) & 1) << 3;
  int boffc[4];
  #pragma unroll
  for (int cc = 0; cc < 4; ++cc) {
    int c = col4 * 4 + cc;
    boffc[cc] = ((c >> 4) << 10) + (SWZ((kseg << 4) + (c & 15)) << 4) + khalf8;
  }

  const unsigned short* qa =
      AO + (((size_t)(lane >> 4)) * PAD_ + m0 + (wr << 6) + (lane & 15)) * 8;

  short8 afE[4], afO[4];
  f32x4 fBE[4], fBO[4];
  f32x4 acc[4][4] = {};

#define F2_ALOAD(SET) do {                                               \
    _Pragma("unroll")                                                    \
    for (int mi = 0; mi < 4; ++mi)                                       \
      af##SET[mi] = *(const short8*)(qa + mi * 128);                     \
    qa += (size_t)4 * PAD_ * 8;                                          \
  } while (0)

#define F2_BLOAD(SET) do {                                               \
    _Pragma("unroll")                                                    \
    for (int j = 0; j < 4; ++j)                                          \
      fB##SET[j] = *(const f32x4*)(qB + (size_t)j * D_);                 \
    qB += (size_t)BK * D_;                                               \
  } while (0)

#define F2_BWRITE(SET, BUF) do {                                         \
    _Pragma("unroll")                                                    \
    for (int cc = 0; cc < 4; ++cc) {                                     \
      s16x4 w;                                                           \
      _Pragma("unroll")                                                  \
      for (int j = 0; j < 4; ++j) w[j] = f2bfs(fB##SET[j][cc]);          \
      *(s16x4*)((char*)Bs + (BUF)*8192 + boffc[cc]) = w;                 \
    }                                                                    \
  } while (0)

#define F2_MFMA(BUF, SET) do {                                           \
    int lsw = SWZ(lane) << 4;                                            \
    __builtin_amdgcn_s_setprio(1);                                       \
    _Pragma("unroll")                                                    \
    for (int q = 0; q < 4; ++q) {                                        \
      short8 bfr = *(const short8*)((char*)Bs + (BUF)*8192 + (((wc << 2) + q) << 10) + lsw); \
      _Pragma("unroll")                                                  \
      for (int mi = 0; mi < 4; ++mi)                                     \
        acc[mi][q] = __builtin_amdgcn_mfma_f32_16x16x32_bf16(af##SET[mi], bfr, acc[mi][q], 0, 0, 0); \
    }                                                                    \
    __builtin_amdgcn_s_setprio(0);                                       \
  } while (0)

  // 44 K-tiles, depth-2, interleaved issue
  F2_ALOAD(E); F2_BLOAD(E);
  F2_ALOAD(O); F2_BLOAD(O);
  for (int it = 0; it < 21; ++it) {
    F2_BWRITE(E, 0); WAIT_LGKM0(); BARS();
    F2_BLOAD(E);
    F2_MFMA(0, E);
    F2_ALOAD(E);
    BARX();
    F2_BWRITE(O, 1); WAIT_LGKM0(); BARS();
    F2_BLOAD(O);
    F2_MFMA(1, O);
    F2_ALOAD(O);
    BARX();
  }
  F2_BWRITE(E, 0); WAIT_LGKM0(); BARS(); F2_MFMA(0, E); BARX();
  F2_BWRITE(O, 1); WAIT_LGKM0(); BARS(); F2_MFMA(1, O);

  // epilogue: coalesced bf16 store of raw acc to eoO[e][m][D]
  unsigned short* eoE = eoO + (size_t)e * PAD_ * D_;
  int lr = (lane >> 4) << 2, lc = lane & 15;
  #pragma unroll
  for (int mi = 0; mi < 4; ++mi) {
    #pragma unroll
    for (int j = 0; j < 4; ++j) {
      int m = m0 + ((wr << 2) + mi) * 16 + lr + j;
      if (m < Me) {
        unsigned short* op = eoE + (size_t)m * D_ + n0 + (wc << 6) + lc;
        #pragma unroll
        for (int q = 0; q < 4; ++q)
          op[q << 4] = (unsigned short)f2bfs(acc[mi][q][j]);
      }
    }
  }
}

// ---------------- combine: y[t] = w1*eo1 + w2*eo2 ----------------
__global__ __launch_bounds__(256) void combine_kernel(
    const unsigned short* __restrict__ eoO, const int* __restrict__ pairE,
    const int* __restrict__ pairM, const float* __restrict__ pairW,
    float* __restrict__ y) {
  int t = blockIdx.x * 4 + (threadIdx.x >> 6);
  int lane = threadIdx.x & 63;
  int e1 = pairE[2 * t], m1 = pairM[2 * t];
  int e2 = pairE[2 * t + 1], m2 = pairM[2 * t + 1];
  float w1 = pairW[2 * t], w2 = pairW[2 * t + 1];
  float out[16];
  #pragma unroll
  for (int i = 0; i < 16; ++i) out[i] = 0.f;
  if (m1 >= 0) {
    const unsigned short* rp = eoO + ((size_t)e1 * PAD_ + m1) * D_ + lane * 16;
    short8 a = *(const short8*)rp, b = *(const short8*)(rp + 8);
    #pragma unroll
    for (int i = 0; i < 8; ++i) {
      out[i]     += w1 * bf2f((unsigned short)a[i]);
      out[8 + i] += w1 * bf2f((unsigned short)b[i]);
    }
  }
  if (m2 >= 0) {
    const unsigned short* rp = eoO + ((size_t)e2 * PAD_ + m2) * D_ + lane * 16;
    short8 a = *(const short8*)rp, b = *(const short8*)(rp + 8);
    #pragma unroll
    for (int i = 0; i < 8; ++i) {
      out[i]     += w2 * bf2f((unsigned short)a[i]);
      out[8 + i] += w2 * bf2f((unsigned short)b[i]);
    }
  }
  int b = t >> 11, s = t & (S_ - 1);
  float* yp = y + (size_t)(s * B_ + b) * D_ + lane * 16;
  #pragma unroll
  for (int v = 0; v < 4; ++v) {
    float4 o4 = make_float4(out[v * 4], out[v * 4 + 1], out[v * 4 + 2], out[v * 4 + 3]);
    *(float4*)(yp + v * 4) = o4;
  }
}

extern "C" void kernel_launch(void* const* d_in, const int* in_sizes, int n_in,
                              void* d_out, int out_size, void* d_ws, size_t ws_size,
                              hipStream_t stream) {
  const float* x  = (const float*)d_in[0];
  const float* Wg = (const float*)d_in[1];
  const float* W1 = (const float*)d_in[2];
  const float* W3 = (const float*)d_in[3];
  const float* W2 = (const float*)d_in[4];
  float* y = (float*)d_out;
  float* laux = y + (size_t)S_ * B_ * D_;

  char* ws = (char*)d_ws;
  float* probs  = (float*)(ws + OFF_PROBS);
  int*   counts = (int*)  (ws + OFF_COUNTS);
  float* mesum  = (float*)(ws + OFF_MESUM);
  int*   pairE  = (int*)  (ws + OFF_PAIRE);
  int*   pairM  = (int*)  (ws + OFF_PAIRM);
  float* pairW  = (float*)(ws + OFF_PAIRW);
  unsigned short* xbufO = (unsigned short*)(ws + OFF_XBUF);  // also eoO
  unsigned short* hO    = (unsigned short*)(ws + OFF_H);

  hipMemsetAsync(counts, 0, 512, stream);

  gate_kernel<<<T_ / 8, 256, 0, stream>>>(x, Wg, probs, counts, pairE, pairM, pairW, xbufO);
  me_kernel<<<E_, 256, 0, stream>>>(probs, mesum);
  finalize_kernel<<<1, 64, 0, stream>>>(counts, mesum, laux);
  ffn1_kernel<<<8 * 8 * 11 * 3, 256, 0, stream>>>(xbufO, W1, W3, counts, hO);
  ffn2_kernel<<<8 * 8 * 8 * 3, 256, 0, stream>>>(hO, W2, counts, xbufO);  // eoO aliases xbufO
  combine_kernel<<<T_ / 4, 256, 0, stream>>>(xbufO, pairE, pairM, pairW, y);
}